// Round 4
// baseline (333.170 us; speedup 1.0000x reference)
//
#include <hip/hip_runtime.h>
#include <math.h>

#define NCLS 100
#define NBINS 15
#define NSEG (NCLS * NBINS)
#define NTOT (2 * NSEG + NCLS)   // conf[1500] | acc[1500] | total[100] = 3100
#define PSTRIDE 3104             // 64B-aligned partial rows (3104*4 = 12416)
#define RPI 8                    // rows per tile (4 slots x 2 rows)
#define GMAIN 2048               // 8 blocks/CU, all-resident (32 waves/CU)
#define SWEEP (GMAIN * 4 * RPI)  // rows per full-grid sweep (65536)

// Native fp32 atomic add (ds_add_f32 / global_atomic_add_f32).
__device__ __forceinline__ void fadd(float* p, float v) { unsafeAtomicAdd(p, v); }

__device__ __forceinline__ float readlane_f(float x, int l) {
    return __builtin_bit_cast(float, __builtin_amdgcn_readlane(__builtin_bit_cast(int, x), l));
}

// DPP wave64 sum step (VALU pipe only).
template <int CTRL>
__device__ __forceinline__ float dpp_add(float x) {
    int y = __builtin_amdgcn_update_dpp(0, __builtin_bit_cast(int, x),
                                        CTRL, 0xf, 0xf, true);
    return x + __builtin_bit_cast(float, y);
}

// ---- macros: everything in named registers, zero helper calls, so nothing
// ---- can be demoted to scratch (round-2 post-mortem: WRITE_SIZE 460MB).

// Unconditional clamp-addressed loads: exactly 5 VMEM ops, no branches ->
// compiler counts vmcnt statically and keeps prefetches in flight.
#define LOAD_TILE(E0, E1, E2, E3, LAB, TB) do {                               \
    (LAB) = labels[min((TB) + lane, N - 1)];                                  \
    const int _f = ((TB) + h) * NCLS + cq;                                    \
    (E0) = *(const float4*)(logits + min(_f,            flim));               \
    (E1) = *(const float4*)(logits + min(_f + 2 * NCLS, flim));               \
    (E2) = *(const float4*)(logits + min(_f + 4 * NCLS, flim));               \
    (E3) = *(const float4*)(logits + min(_f + 6 * NCLS, flim));               \
} while (0)

// exp then zero invalid lanes/rows (cndmask with inline 0; clamped loads
// always read real finite logits, so exp never overflows). Zeroed E also
// guarantees the tails never fire for inactive lanes (p==0 paths).
#define EXPMASK(E, SOUT, VM) do {                                             \
    float _ex = __expf((E).x), _ey = __expf((E).y);                           \
    float _ez = __expf((E).z), _ew = __expf((E).w);                           \
    (E).x = (VM) ? _ex : 0.f; (E).y = (VM) ? _ey : 0.f;                       \
    (E).z = (VM) ? _ez : 0.f; (E).w = (VM) ? _ew : 0.f;                       \
    SOUT = ((E).x + (E).y) + ((E).z + (E).w);                                 \
} while (0)

// Fast-path tail: pf>1 <=> bin>=1 (same arithmetic as the bin calc);
// slow path only for hot probs (~1%) or the label class (1 lane/row).
#define CLS_TAIL(EV, J, INV, LABV) do {                                       \
    const float _p = (EV) * (INV);                                            \
    t##J += _p;                                                               \
    const float _pf = _p * 15.f;                                              \
    const bool _ch = _pf > 1.0f;                                              \
    const bool _lh = (cq + (J)) == (LABV);                                    \
    if (_ch || _lh) {                                                         \
        const int _b = min((int)ceilf(_pf) - 1, NBINS - 1);                   \
        if (_ch) fadd(&s_conf[(cq + (J)) * NBINS + _b], _p);                  \
        if (_lh) fadd(&s_acc[(cq + (J)) * NBINS + max(_b, 0)], 1.f);          \
    }                                                                         \
} while (0)

#define SLOT_TAIL(E, K, SV, TB, LAB, FULLV) do {                              \
    const float _te = readlane_f(SV, 31);                                     \
    const float _to = readlane_f(SV, 63);                                     \
    const float _inv = __builtin_amdgcn_rcpf(fmaxf(h ? _to : _te, 1e-30f));   \
    int _le = __builtin_amdgcn_readlane(LAB, 2 * (K));                        \
    int _lo = __builtin_amdgcn_readlane(LAB, 2 * (K) + 1);                    \
    if (!(FULLV)) {                                                           \
        if ((TB) + 2 * (K)     >= N) _le = -1;                                \
        if ((TB) + 2 * (K) + 1 >= N) _lo = -1;                                \
    }                                                                         \
    const int _lab = h ? _lo : _le;                                           \
    CLS_TAIL((E).x, 0, _inv, _lab);                                           \
    CLS_TAIL((E).y, 1, _inv, _lab);                                           \
    CLS_TAIL((E).z, 2, _inv, _lab);                                           \
    CLS_TAIL((E).w, 3, _inv, _lab);                                           \
} while (0)

// Slot k covers rows TB+2k (half h=0) and TB+2k+1 (half h=1).
// 32-lane DPP reduce: lane31 = even-row total, lane63 = odd-row total.
#define COMPUTE_TILE(E0, E1, E2, E3, LAB, TB, FULLV) do {                     \
    const bool _v0 = act && ((FULLV) || ((TB) + 0 + h) < N);                  \
    const bool _v1 = act && ((FULLV) || ((TB) + 2 + h) < N);                  \
    const bool _v2 = act && ((FULLV) || ((TB) + 4 + h) < N);                  \
    const bool _v3 = act && ((FULLV) || ((TB) + 6 + h) < N);                  \
    float _s0, _s1, _s2, _s3;                                                 \
    EXPMASK(E0, _s0, _v0); EXPMASK(E1, _s1, _v1);                             \
    EXPMASK(E2, _s2, _v2); EXPMASK(E3, _s3, _v3);                             \
    _s0 = dpp_add<0x111>(_s0); _s1 = dpp_add<0x111>(_s1);                     \
    _s2 = dpp_add<0x111>(_s2); _s3 = dpp_add<0x111>(_s3);                     \
    _s0 = dpp_add<0x112>(_s0); _s1 = dpp_add<0x112>(_s1);                     \
    _s2 = dpp_add<0x112>(_s2); _s3 = dpp_add<0x112>(_s3);                     \
    _s0 = dpp_add<0x114>(_s0); _s1 = dpp_add<0x114>(_s1);                     \
    _s2 = dpp_add<0x114>(_s2); _s3 = dpp_add<0x114>(_s3);                     \
    _s0 = dpp_add<0x118>(_s0); _s1 = dpp_add<0x118>(_s1);                     \
    _s2 = dpp_add<0x118>(_s2); _s3 = dpp_add<0x118>(_s3);                     \
    _s0 = dpp_add<0x142>(_s0); _s1 = dpp_add<0x142>(_s1);                     \
    _s2 = dpp_add<0x142>(_s2); _s3 = dpp_add<0x142>(_s3);                     \
    SLOT_TAIL(E0, 0, _s0, TB, LAB, FULLV);                                    \
    SLOT_TAIL(E1, 1, _s1, TB, LAB, FULLV);                                    \
    SLOT_TAIL(E2, 2, _s2, TB, LAB, FULLV);                                    \
    SLOT_TAIL(E3, 3, _s3, TB, LAB, FULLV);                                    \
} while (0)

// lb(256,8): VGPR cap 64 -> 8 blocks/CU (32 waves/CU, 8 waves/SIMD).
// Depth-2 ping-pong: A+B data = 32 VGPR; round-0 proved the op fits 28.
__global__ __launch_bounds__(256, 8) void ece_main_kernel(
    const float* __restrict__ logits,
    const int* __restrict__ labels,
    float* __restrict__ g_hist,     // [NTOT] (fallback atomic path)
    float* __restrict__ parts,      // [GMAIN][PSTRIDE] or nullptr
    int N)
{
    __shared__ float s_conf[NSEG];
    __shared__ float s_acc[NSEG];
    __shared__ float s_total[NCLS];
    for (int i = threadIdx.x; i < NSEG; i += 256) { s_conf[i] = 0.f; s_acc[i] = 0.f; }
    if (threadIdx.x < NCLS) s_total[threadIdx.x] = 0.f;
    __syncthreads();

    const int lane  = threadIdx.x & 63;
    const int wave  = threadIdx.x >> 6;
    const int gwave = blockIdx.x * 4 + wave;
    const int q     = lane & 31;            // class quad within half-wave
    const int h     = lane >> 5;            // row of the pair
    const int cq    = 4 * q;
    const bool act  = (q < NCLS / 4);       // q 0..24 hold classes
    const int flim  = N * NCLS - 4;         // clamp keeps dwordx4 in-bounds+aligned

    float t0 = 0.f, t1 = 0.f, t2 = 0.f, t3 = 0.f;
    float4 A0, A1, A2, A3, B0, B1, B2, B3;
    int labA, labB;
    int base = gwave * RPI;                 // max 65528 < N: every wave has work

    // Depth-2 ping-pong, 2x unrolled so buffers are statically named.
    LOAD_TILE(A0, A1, A2, A3, labA, base);
    while (base + SWEEP + RPI <= N) {       // tiles at base and base+SWEEP full
        LOAD_TILE(B0, B1, B2, B3, labB, base + SWEEP);
        __builtin_amdgcn_sched_barrier(0);
        COMPUTE_TILE(A0, A1, A2, A3, labA, base, true);
        LOAD_TILE(A0, A1, A2, A3, labA, base + 2 * SWEEP);   // clamped: safe OOB
        __builtin_amdgcn_sched_barrier(0);
        COMPUTE_TILE(B0, B1, B2, B3, labB, base + SWEEP, true);
        base += 2 * SWEEP;
    }
    // Epilogue: tile(base) is in A (possibly partial); at most one more
    // partial tile at base+SWEEP (loop exit implies base+2*SWEEP >= N).
    if (base < N) COMPUTE_TILE(A0, A1, A2, A3, labA, base, false);
    if (base + SWEEP < N) {
        LOAD_TILE(B0, B1, B2, B3, labB, base + SWEEP);
        COMPUTE_TILE(B0, B1, B2, B3, labB, base + SWEEP, false);
    }

    // Both halves hold totals for the same classes; LDS atomics merge.
    if (act) {
        fadd(&s_total[cq + 0], t0);
        fadd(&s_total[cq + 1], t1);
        fadd(&s_total[cq + 2], t2);
        fadd(&s_total[cq + 3], t3);
    }
    __syncthreads();

    if (parts) {
        // Two-stage path: stream block-private histogram, no atomics.
        float* my = parts + (size_t)blockIdx.x * PSTRIDE;
        for (int i = threadIdx.x; i < NSEG; i += 256) {
            __builtin_nontemporal_store(s_conf[i], &my[i]);
            __builtin_nontemporal_store(s_acc[i], &my[NSEG + i]);
        }
        if (threadIdx.x < NCLS)
            __builtin_nontemporal_store(s_total[threadIdx.x], &my[2 * NSEG + threadIdx.x]);
    } else {
        // Fallback: global-atomic flush (g_hist pre-zeroed by host).
        for (int i = threadIdx.x; i < NSEG; i += 256) {
            float v = s_conf[i]; if (v != 0.f) fadd(&g_hist[i], v);
            float a = s_acc[i];  if (a != 0.f) fadd(&g_hist[NSEG + i], a);
        }
        if (threadIdx.x < NCLS) {
            float tt = s_total[threadIdx.x];
            if (tt != 0.f) fadd(&g_hist[2 * NSEG + threadIdx.x], tt);
        }
    }
}

// Stage 2: fold GMAIN partials into g_hist. One writer per cell (plain
// store) -> no atomics, no pre-zero needed. 1024 thr = 16 waves; wave w
// sums chunk w (GMAIN/16 partials); lanes = 64 consecutive cells (256B).
__global__ __launch_bounds__(1024) void ece_reduce_kernel(
    const float* __restrict__ parts, float* __restrict__ g_hist, int nparts)
{
    const int lane = threadIdx.x & 63;
    const int wave = threadIdx.x >> 6;          // 0..15
    const int cell = blockIdx.x * 64 + lane;
    const int per = nparts / 16;
    float s = 0.f;
    if (cell < NTOT) {
        const float* bp = parts + (size_t)wave * per * PSTRIDE + cell;
        #pragma unroll 8
        for (int p = 0; p < per; ++p)
            s += __builtin_nontemporal_load(&bp[(size_t)p * PSTRIDE]);
    }
    __shared__ float red[16][64];
    red[wave][lane] = s;
    __syncthreads();
    if (wave == 0) {
        float v = 0.f;
        #pragma unroll
        for (int w = 0; w < 16; ++w) v += red[w][lane];
        if (cell < NTOT) g_hist[cell] = v;
    }
}

// Finalize: conf0 = total - sum_{b>=1} conf_b; per-class sce; mean.
__global__ __launch_bounds__(128) void ece_final_kernel(
    const float* __restrict__ g_hist,
    float* __restrict__ out,
    float invN)
{
    __shared__ float red[128];
    const int t = threadIdx.x;
    float s = 0.f;
    if (t < NCLS) {
        float conf0 = g_hist[2 * NSEG + t];
        float sum = 0.f;
        #pragma unroll
        for (int b = 1; b < NBINS; ++b) {
            float cb = g_hist[t * NBINS + b];
            float ab = g_hist[NSEG + t * NBINS + b];
            conf0 -= cb;
            sum += fabsf(cb - ab);
        }
        sum += fabsf(conf0 - g_hist[NSEG + t * NBINS + 0]);
        s = sum * invN;
        out[1 + t] = s;
    }
    red[t] = s;
    __syncthreads();
    #pragma unroll
    for (int off = 64; off > 0; off >>= 1) {
        if (t < off) red[t] += red[t + off];
        __syncthreads();
    }
    if (t == 0) out[0] = red[0] * (1.0f / (float)NCLS);
}

extern "C" void kernel_launch(void* const* d_in, const int* in_sizes, int n_in,
                              void* d_out, int out_size, void* d_ws, size_t ws_size,
                              hipStream_t stream)
{
    const float* logits = (const float*)d_in[0];
    const int*   labels = (const int*)d_in[1];
    const int N = in_sizes[1];
    float* out = (float*)d_out;

    float* g_hist = (float*)d_ws;                         // [NTOT]
    const size_t parts_off = ((size_t)NTOT * sizeof(float) + 255) & ~(size_t)255;
    const size_t need = parts_off + (size_t)GMAIN * PSTRIDE * sizeof(float);
    float* parts = (ws_size >= need) ? (float*)((char*)d_ws + parts_off) : nullptr;

    if (!parts)   // atomic fallback needs a zeroed g_hist; two-stage does not
        (void)hipMemsetAsync(d_ws, 0, (size_t)NTOT * sizeof(float), stream);

    ece_main_kernel<<<GMAIN, 256, 0, stream>>>(logits, labels, g_hist, parts, N);
    if (parts)
        ece_reduce_kernel<<<(NTOT + 63) / 64, 1024, 0, stream>>>(parts, g_hist, GMAIN);
    ece_final_kernel<<<1, 128, 0, stream>>>(g_hist, out, 1.0f / (float)N);
}

// Round 5
// 296.190 us; speedup vs baseline: 1.1249x; 1.1249x over previous
//
#include <hip/hip_runtime.h>
#include <math.h>

#define NCLS 100
#define NBINS 15
#define NSEG (NCLS * NBINS)
#define NTOT (2 * NSEG + NCLS)   // conf[1500] | acc[1500] | total[100] = 3100
#define PSTRIDE 3104             // 64B-aligned partial rows (3104*4 = 12416)
#define RPI 8                    // rows per tile (4 slots x 2 rows)
#define GMAIN 1536               // 6 blocks/CU, all-resident (24 waves/CU)
#define SWEEP (GMAIN * 4 * RPI)  // rows per full-grid sweep (49152)

// Native fp32 atomic add (ds_add_f32 / global_atomic_add_f32).
__device__ __forceinline__ void fadd(float* p, float v) { unsafeAtomicAdd(p, v); }

__device__ __forceinline__ float readlane_f(float x, int l) {
    return __builtin_bit_cast(float, __builtin_amdgcn_readlane(__builtin_bit_cast(int, x), l));
}

// DPP wave64 sum step (VALU pipe only).
template <int CTRL>
__device__ __forceinline__ float dpp_add(float x) {
    int y = __builtin_amdgcn_update_dpp(0, __builtin_bit_cast(int, x),
                                        CTRL, 0xf, 0xf, true);
    return x + __builtin_bit_cast(float, y);
}

// ---- macros: everything in named registers, zero helper calls, so nothing
// ---- can be demoted to scratch (round-2 post-mortem: WRITE_SIZE 460MB).

// Unconditional clamp-addressed loads: exactly 5 VMEM ops, no branches.
// cqc = min(4q, 96): inactive lanes (q>=25) re-read the row's last 16B ->
// per-row footprint exactly 400B, no next-row overfetch (round-4 had 512B).
// Flat clamp to flim only triggers for OOB prefetch/epilogue tiles.
#define LOAD_TILE(E0, E1, E2, E3, LAB, TB) do {                               \
    (LAB) = labels[min((TB) + lane, N - 1)];                                  \
    const int _f = ((TB) + h) * NCLS + cqc;                                   \
    (E0) = *(const float4*)(logits + min(_f,            flim));               \
    (E1) = *(const float4*)(logits + min(_f + 2 * NCLS, flim));               \
    (E2) = *(const float4*)(logits + min(_f + 4 * NCLS, flim));               \
    (E3) = *(const float4*)(logits + min(_f + 6 * NCLS, flim));               \
} while (0)

// exp then zero invalid lanes/rows (cndmask with inline 0; clamped loads
// always read real finite logits, so exp never overflows). Zeroed E also
// guarantees the tails never fire for inactive lanes (p==0 paths).
#define EXPMASK(E, SOUT, VM) do {                                             \
    float _ex = __expf((E).x), _ey = __expf((E).y);                           \
    float _ez = __expf((E).z), _ew = __expf((E).w);                           \
    (E).x = (VM) ? _ex : 0.f; (E).y = (VM) ? _ey : 0.f;                       \
    (E).z = (VM) ? _ez : 0.f; (E).w = (VM) ? _ew : 0.f;                       \
    SOUT = ((E).x + (E).y) + ((E).z + (E).w);                                 \
} while (0)

// Fast-path tail: pf>1 <=> bin>=1 (same arithmetic as the bin calc);
// slow path only for hot probs (~1%) or the label class (1 lane/row).
// NOTE: uses cq (true class id, may be >=100) so inactive lanes never match.
#define CLS_TAIL(EV, J, INV, LABV) do {                                       \
    const float _p = (EV) * (INV);                                            \
    t##J += _p;                                                               \
    const float _pf = _p * 15.f;                                              \
    const bool _ch = _pf > 1.0f;                                              \
    const bool _lh = (cq + (J)) == (LABV);                                    \
    if (_ch || _lh) {                                                         \
        const int _b = min((int)ceilf(_pf) - 1, NBINS - 1);                   \
        if (_ch) fadd(&s_conf[(cq + (J)) * NBINS + _b], _p);                  \
        if (_lh) fadd(&s_acc[(cq + (J)) * NBINS + max(_b, 0)], 1.f);          \
    }                                                                         \
} while (0)

#define SLOT_TAIL(E, K, SV, TB, LAB, FULLV) do {                              \
    const float _te = readlane_f(SV, 31);                                     \
    const float _to = readlane_f(SV, 63);                                     \
    const float _inv = __builtin_amdgcn_rcpf(fmaxf(h ? _to : _te, 1e-30f));   \
    int _le = __builtin_amdgcn_readlane(LAB, 2 * (K));                        \
    int _lo = __builtin_amdgcn_readlane(LAB, 2 * (K) + 1);                    \
    if (!(FULLV)) {                                                           \
        if ((TB) + 2 * (K)     >= N) _le = -1;                                \
        if ((TB) + 2 * (K) + 1 >= N) _lo = -1;                                \
    }                                                                         \
    const int _lab = h ? _lo : _le;                                           \
    CLS_TAIL((E).x, 0, _inv, _lab);                                           \
    CLS_TAIL((E).y, 1, _inv, _lab);                                           \
    CLS_TAIL((E).z, 2, _inv, _lab);                                           \
    CLS_TAIL((E).w, 3, _inv, _lab);                                           \
} while (0)

// Slot k covers rows TB+2k (half h=0) and TB+2k+1 (half h=1).
// 32-lane DPP reduce: lane31 = even-row total, lane63 = odd-row total.
#define COMPUTE_TILE(E0, E1, E2, E3, LAB, TB, FULLV) do {                     \
    const bool _v0 = act && ((FULLV) || ((TB) + 0 + h) < N);                  \
    const bool _v1 = act && ((FULLV) || ((TB) + 2 + h) < N);                  \
    const bool _v2 = act && ((FULLV) || ((TB) + 4 + h) < N);                  \
    const bool _v3 = act && ((FULLV) || ((TB) + 6 + h) < N);                  \
    float _s0, _s1, _s2, _s3;                                                 \
    EXPMASK(E0, _s0, _v0); EXPMASK(E1, _s1, _v1);                             \
    EXPMASK(E2, _s2, _v2); EXPMASK(E3, _s3, _v3);                             \
    _s0 = dpp_add<0x111>(_s0); _s1 = dpp_add<0x111>(_s1);                     \
    _s2 = dpp_add<0x111>(_s2); _s3 = dpp_add<0x111>(_s3);                     \
    _s0 = dpp_add<0x112>(_s0); _s1 = dpp_add<0x112>(_s1);                     \
    _s2 = dpp_add<0x112>(_s2); _s3 = dpp_add<0x112>(_s3);                     \
    _s0 = dpp_add<0x114>(_s0); _s1 = dpp_add<0x114>(_s1);                     \
    _s2 = dpp_add<0x114>(_s2); _s3 = dpp_add<0x114>(_s3);                     \
    _s0 = dpp_add<0x118>(_s0); _s1 = dpp_add<0x118>(_s1);                     \
    _s2 = dpp_add<0x118>(_s2); _s3 = dpp_add<0x118>(_s3);                     \
    _s0 = dpp_add<0x142>(_s0); _s1 = dpp_add<0x142>(_s1);                     \
    _s2 = dpp_add<0x142>(_s2); _s3 = dpp_add<0x142>(_s3);                     \
    SLOT_TAIL(E0, 0, _s0, TB, LAB, FULLV);                                    \
    SLOT_TAIL(E1, 1, _s1, TB, LAB, FULLV);                                    \
    SLOT_TAIL(E2, 2, _s2, TB, LAB, FULLV);                                    \
    SLOT_TAIL(E3, 3, _s3, TB, LAB, FULLV);                                    \
} while (0)

// lb(256,6): VGPR cap ~85 -> 6 blocks/CU (24 waves/CU). Depth-2 ping-pong
// needs ~60 VGPR -> 25 regs of slack so the compiler cannot spill (round-4
// post-mortem: lb(256,8)'s cap-64 was right at the live-range edge and the
// spill traffic showed as WRITE_SIZE 111MB vs 25MB logical).
__global__ __launch_bounds__(256, 6) void ece_main_kernel(
    const float* __restrict__ logits,
    const int* __restrict__ labels,
    float* __restrict__ g_hist,     // [NTOT] (fallback atomic path)
    float* __restrict__ parts,      // [GMAIN][PSTRIDE] or nullptr
    int N)
{
    __shared__ float s_conf[NSEG];
    __shared__ float s_acc[NSEG];
    __shared__ float s_total[NCLS];
    for (int i = threadIdx.x; i < NSEG; i += 256) { s_conf[i] = 0.f; s_acc[i] = 0.f; }
    if (threadIdx.x < NCLS) s_total[threadIdx.x] = 0.f;
    __syncthreads();

    const int lane  = threadIdx.x & 63;
    const int wave  = threadIdx.x >> 6;
    const int gwave = blockIdx.x * 4 + wave;
    const int q     = lane & 31;            // class quad within half-wave
    const int h     = lane >> 5;            // row of the pair
    const int cq    = 4 * q;                // true class id (>=100 for pads)
    const int cqc   = min(cq, NCLS - 4);    // load offset: stay inside the row
    const bool act  = (q < NCLS / 4);       // q 0..24 hold classes
    const int flim  = N * NCLS - 4;         // flat clamp for OOB tiles only

    float t0 = 0.f, t1 = 0.f, t2 = 0.f, t3 = 0.f;
    float4 A0, A1, A2, A3, B0, B1, B2, B3;
    int labA, labB;
    int base = gwave * RPI;                 // max 49144 < N: every wave has work

    // Depth-2 ping-pong, 2x unrolled so buffers are statically named.
    LOAD_TILE(A0, A1, A2, A3, labA, base);
    while (base + SWEEP + RPI <= N) {       // tiles at base and base+SWEEP full
        LOAD_TILE(B0, B1, B2, B3, labB, base + SWEEP);
        __builtin_amdgcn_sched_barrier(0);
        COMPUTE_TILE(A0, A1, A2, A3, labA, base, true);
        LOAD_TILE(A0, A1, A2, A3, labA, base + 2 * SWEEP);   // clamped: safe OOB
        __builtin_amdgcn_sched_barrier(0);
        COMPUTE_TILE(B0, B1, B2, B3, labB, base + SWEEP, true);
        base += 2 * SWEEP;
    }
    // Epilogue: tile(base) is in A (possibly partial); at most one more
    // partial tile at base+SWEEP (loop exit implies base+2*SWEEP >= N).
    if (base < N) COMPUTE_TILE(A0, A1, A2, A3, labA, base, false);
    if (base + SWEEP < N) {
        LOAD_TILE(B0, B1, B2, B3, labB, base + SWEEP);
        COMPUTE_TILE(B0, B1, B2, B3, labB, base + SWEEP, false);
    }

    // Both halves hold totals for the same classes; LDS atomics merge.
    if (act) {
        fadd(&s_total[cq + 0], t0);
        fadd(&s_total[cq + 1], t1);
        fadd(&s_total[cq + 2], t2);
        fadd(&s_total[cq + 3], t3);
    }
    __syncthreads();

    if (parts) {
        // Two-stage path: stream block-private histogram (plain stores;
        // round-4 used nontemporal which is a suspect for 4.4x write amp).
        float* my = parts + (size_t)blockIdx.x * PSTRIDE;
        for (int i = threadIdx.x; i < NSEG; i += 256) {
            my[i] = s_conf[i];
            my[NSEG + i] = s_acc[i];
        }
        if (threadIdx.x < NCLS)
            my[2 * NSEG + threadIdx.x] = s_total[threadIdx.x];
    } else {
        // Fallback: global-atomic flush (g_hist pre-zeroed by host).
        for (int i = threadIdx.x; i < NSEG; i += 256) {
            float v = s_conf[i]; if (v != 0.f) fadd(&g_hist[i], v);
            float a = s_acc[i];  if (a != 0.f) fadd(&g_hist[NSEG + i], a);
        }
        if (threadIdx.x < NCLS) {
            float tt = s_total[threadIdx.x];
            if (tt != 0.f) fadd(&g_hist[2 * NSEG + threadIdx.x], tt);
        }
    }
}

// Stage 2: fold GMAIN partials into g_hist. One writer per cell (plain
// store) -> no atomics, no pre-zero needed. 1024 thr = 16 waves; wave w
// sums chunk w (GMAIN/16 partials); lanes = 64 consecutive cells (256B).
__global__ __launch_bounds__(1024) void ece_reduce_kernel(
    const float* __restrict__ parts, float* __restrict__ g_hist, int nparts)
{
    const int lane = threadIdx.x & 63;
    const int wave = threadIdx.x >> 6;          // 0..15
    const int cell = blockIdx.x * 64 + lane;
    const int per = nparts / 16;
    float s = 0.f;
    if (cell < NTOT) {
        const float* bp = parts + (size_t)wave * per * PSTRIDE + cell;
        #pragma unroll 8
        for (int p = 0; p < per; ++p)
            s += bp[(size_t)p * PSTRIDE];
    }
    __shared__ float red[16][64];
    red[wave][lane] = s;
    __syncthreads();
    if (wave == 0) {
        float v = 0.f;
        #pragma unroll
        for (int w = 0; w < 16; ++w) v += red[w][lane];
        if (cell < NTOT) g_hist[cell] = v;
    }
}

// Finalize: conf0 = total - sum_{b>=1} conf_b; per-class sce; mean.
__global__ __launch_bounds__(128) void ece_final_kernel(
    const float* __restrict__ g_hist,
    float* __restrict__ out,
    float invN)
{
    __shared__ float red[128];
    const int t = threadIdx.x;
    float s = 0.f;
    if (t < NCLS) {
        float conf0 = g_hist[2 * NSEG + t];
        float sum = 0.f;
        #pragma unroll
        for (int b = 1; b < NBINS; ++b) {
            float cb = g_hist[t * NBINS + b];
            float ab = g_hist[NSEG + t * NBINS + b];
            conf0 -= cb;
            sum += fabsf(cb - ab);
        }
        sum += fabsf(conf0 - g_hist[NSEG + t * NBINS + 0]);
        s = sum * invN;
        out[1 + t] = s;
    }
    red[t] = s;
    __syncthreads();
    #pragma unroll
    for (int off = 64; off > 0; off >>= 1) {
        if (t < off) red[t] += red[t + off];
        __syncthreads();
    }
    if (t == 0) out[0] = red[0] * (1.0f / (float)NCLS);
}

extern "C" void kernel_launch(void* const* d_in, const int* in_sizes, int n_in,
                              void* d_out, int out_size, void* d_ws, size_t ws_size,
                              hipStream_t stream)
{
    const float* logits = (const float*)d_in[0];
    const int*   labels = (const int*)d_in[1];
    const int N = in_sizes[1];
    float* out = (float*)d_out;

    float* g_hist = (float*)d_ws;                         // [NTOT]
    const size_t parts_off = ((size_t)NTOT * sizeof(float) + 255) & ~(size_t)255;
    const size_t need = parts_off + (size_t)GMAIN * PSTRIDE * sizeof(float);
    float* parts = (ws_size >= need) ? (float*)((char*)d_ws + parts_off) : nullptr;

    if (!parts)   // atomic fallback needs a zeroed g_hist; two-stage does not
        (void)hipMemsetAsync(d_ws, 0, (size_t)NTOT * sizeof(float), stream);

    ece_main_kernel<<<GMAIN, 256, 0, stream>>>(logits, labels, g_hist, parts, N);
    if (parts)
        ece_reduce_kernel<<<(NTOT + 63) / 64, 1024, 0, stream>>>(parts, g_hist, GMAIN);
    ece_final_kernel<<<1, 128, 0, stream>>>(g_hist, out, 1.0f / (float)N);
}